// Round 4
// baseline (4505.253 us; speedup 1.0000x reference)
//
#include <hip/hip_runtime.h>
#include <hip/hip_fp16.h>
#include <stdint.h>

#define T_STEPS 1024
#define HDIM    128
#define NT      512

// Thread mapping (the core of the 2-barrier design):
//   wave w = tid>>6, lane l = tid&63
//   element e = 16*w + (l&15)        (0..127)
//   gate    g = l>>4                 (0:i 1:f 2:g 3:o)
//   row       = 128*g + e            (gate row of the 4H x H matrices)
// => the 4 gates of element e live in lanes l, l^16, l^32, l^48 of ONE wave,
//    so the LSTM cell update is 3 shfl_xor + a few VALU — no LDS, no barrier.

// ---- packed f16-pair types --------------------------------------------------
typedef _Float16 v2h __attribute__((ext_vector_type(2)));
union HU { uint32_t u; v2h v; };

__device__ __forceinline__ float dot2h(uint32_t a, uint32_t b, float c) {
    HU ua, ub; ua.u = a; ub.u = b;
    return __builtin_amdgcn_fdot2(ua.v, ub.v, c, false);  // v_dot2_f32_f16
}
__device__ __forceinline__ uint32_t packh2f(float2 e) {
    return (uint32_t)__half_as_ushort(__float2half_rn(e.x)) |
           ((uint32_t)__half_as_ushort(__float2half_rn(e.y)) << 16);
}
__device__ __forceinline__ uint16_t f2h(float f) {
    return __half_as_ushort(__float2half_rn(f));
}
// act(a,1) = sigmoid(a); act(a,2) = tanh(a).  1 exp + 1 fast-rcp.
__device__ __forceinline__ float actf(float a, float m) {
    return 1.0f - m * __builtin_amdgcn_rcpf(__expf(m * a) + 1.0f);
}

// Scheduling fence: bounds how many LDS-read temps stay live, keeping peak
// arch-VGPR demand under 256 (over => allocator exiles weights out of the
// addressable file and every dot2 pays a move — R2's 43%-VALU/128-VGPR
// signature at an unmoved 2.1 ms).
#define SB() __builtin_amdgcn_sched_barrier(0)

// Opaque per-component register pin: forbids rematerialization and forces
// arch-VGPR residency at this point. MUST be component-wise — "+v" on a
// uint4 is a tied indirect register input (unsupported, R3 compile fail).
#define PIN4(W) asm volatile("" : "+v"(W.x), "+v"(W.y), "+v"(W.z), "+v"(W.w))

#define SETW4(W, r2, j)                                                    \
    W = make_uint4(packh2f((r2)[4*(j)+0]), packh2f((r2)[4*(j)+1]),         \
                   packh2f((r2)[4*(j)+2]), packh2f((r2)[4*(j)+3]))

// 16 dot2s: 4 register weight uint4s vs broadcast h quarter q from LDS.
#define DOTQ4(WA, WB, WC, WD, Hv, q, acc) do {                             \
    uint4 _p0 = (Hv)[4*(q)+0], _p1 = (Hv)[4*(q)+1];                        \
    uint4 _p2 = (Hv)[4*(q)+2], _p3 = (Hv)[4*(q)+3];                        \
    acc = dot2h(WA.x, _p0.x, acc); acc = dot2h(WA.y, _p0.y, acc);          \
    acc = dot2h(WA.z, _p0.z, acc); acc = dot2h(WA.w, _p0.w, acc);          \
    acc = dot2h(WB.x, _p1.x, acc); acc = dot2h(WB.y, _p1.y, acc);          \
    acc = dot2h(WB.z, _p1.z, acc); acc = dot2h(WB.w, _p1.w, acc);          \
    acc = dot2h(WC.x, _p2.x, acc); acc = dot2h(WC.y, _p2.y, acc);          \
    acc = dot2h(WC.z, _p2.z, acc); acc = dot2h(WC.w, _p2.w, acc);          \
    acc = dot2h(WD.x, _p3.x, acc); acc = dot2h(WD.y, _p3.y, acc);          \
    acc = dot2h(WD.z, _p3.z, acc); acc = dot2h(WD.w, _p3.w, acc);          \
} while (0)

// W_hh2 lives in LDS, 16 uint4 per thread-row, XOR-swizzled at uint4
// granularity: logical j stored at j^(tid&7). Row stride 256 B (no pad):
// for a fixed logical j across the wave, (j^(tid&7)) spans all 8 sub-slots
// -> the 8 lanes of each group cover all 32 banks. (A +1-uint4 pad would
// give gcd(68,32)=4 -> only 8 banks -> 8-way conflict.)
#define LOADW(U0, U1, U2, U3, q) do {                                      \
    U0 = Wv[wbase + ((4*(q)+0) ^ sw)];                                     \
    U1 = Wv[wbase + ((4*(q)+1) ^ sw)];                                     \
    U2 = Wv[wbase + ((4*(q)+2) ^ sw)];                                     \
    U3 = Wv[wbase + ((4*(q)+3) ^ sw)];                                     \
} while (0)

__global__ __launch_bounds__(NT, 1) void lstm_persistent(
    const float* __restrict__ x,
    const float* __restrict__ W_ih1, const float* __restrict__ W_hh1,
    const float* __restrict__ b_ih1, const float* __restrict__ b_hh1,
    const float* __restrict__ W_ih2, const float* __restrict__ W_hh2,
    const float* __restrict__ b_ih2, const float* __restrict__ b_hh2,
    const float* __restrict__ W_out, const float* __restrict__ b_out,
    float* __restrict__ out)
{
    const int b   = blockIdx.x;
    const int tid = threadIdx.x;
    const int w   = tid >> 6;
    const int l   = tid & 63;
    const int e   = (w << 4) | (l & 15);
    const int gs  = l >> 4;
    const int row = (gs << 7) | e;
    const int sw  = tid & 7;

    __shared__ __align__(16) uint4    wlds[NT * 16];   // W_hh2 f16, 128 KB
    __shared__ __align__(16) uint32_t h1p[2][HDIM/2];  // h1 f16 pairs, dbuf
    __shared__ __align__(16) uint32_t h2p[2][HDIM/2];  // h2 f16 pairs, dbuf
    __shared__ float pbuf[8];                          // per-wave out partials

    // ---- one-time: W_hh1 / W_ih2 rows -> 32 named uint4 (128 dwords)
    uint4 w1_0,w1_1,w1_2,w1_3,w1_4,w1_5,w1_6,w1_7;
    uint4 w1_8,w1_9,w1_10,w1_11,w1_12,w1_13,w1_14,w1_15;
    uint4 w2_0,w2_1,w2_2,w2_3,w2_4,w2_5,w2_6,w2_7;
    uint4 w2_8,w2_9,w2_10,w2_11,w2_12,w2_13,w2_14,w2_15;
    {
        const float2* r1 = (const float2*)(W_hh1 + row * HDIM);
        const float2* r2 = (const float2*)(W_ih2 + row * HDIM);
        SETW4(w1_0,r1,0);  SETW4(w1_1,r1,1);  SETW4(w1_2,r1,2);  SETW4(w1_3,r1,3);
        SETW4(w1_4,r1,4);  SETW4(w1_5,r1,5);  SETW4(w1_6,r1,6);  SETW4(w1_7,r1,7);
        SETW4(w1_8,r1,8);  SETW4(w1_9,r1,9);  SETW4(w1_10,r1,10);SETW4(w1_11,r1,11);
        SETW4(w1_12,r1,12);SETW4(w1_13,r1,13);SETW4(w1_14,r1,14);SETW4(w1_15,r1,15);
        SETW4(w2_0,r2,0);  SETW4(w2_1,r2,1);  SETW4(w2_2,r2,2);  SETW4(w2_3,r2,3);
        SETW4(w2_4,r2,4);  SETW4(w2_5,r2,5);  SETW4(w2_6,r2,6);  SETW4(w2_7,r2,7);
        SETW4(w2_8,r2,8);  SETW4(w2_9,r2,9);  SETW4(w2_10,r2,10);SETW4(w2_11,r2,11);
        SETW4(w2_12,r2,12);SETW4(w2_13,r2,13);SETW4(w2_14,r2,14);SETW4(w2_15,r2,15);
    }
    PIN4(w1_0);  PIN4(w1_1);  PIN4(w1_2);  PIN4(w1_3);
    PIN4(w1_4);  PIN4(w1_5);  PIN4(w1_6);  PIN4(w1_7);
    PIN4(w1_8);  PIN4(w1_9);  PIN4(w1_10); PIN4(w1_11);
    PIN4(w1_12); PIN4(w1_13); PIN4(w1_14); PIN4(w1_15);
    PIN4(w2_0);  PIN4(w2_1);  PIN4(w2_2);  PIN4(w2_3);
    PIN4(w2_4);  PIN4(w2_5);  PIN4(w2_6);  PIN4(w2_7);
    PIN4(w2_8);  PIN4(w2_9);  PIN4(w2_10); PIN4(w2_11);
    PIN4(w2_12); PIN4(w2_13); PIN4(w2_14); PIN4(w2_15);

    // ---- one-time: W_hh2 row -> LDS, swizzled
    const int wbase = tid * 16;
    {
        const float2* r3 = (const float2*)(W_hh2 + row * HDIM);
#pragma unroll
        for (int j = 0; j < 16; ++j) {
            uint4 v;
            SETW4(v, r3, j);
            wlds[wbase + (j ^ sw)] = v;
        }
    }
    const float bias1 = b_ih1[row] + b_hh1[row];
    const float bias2 = b_ih2[row] + b_hh2[row];
    const float wih1  = W_ih1[row];
    const float mm    = (gs == 2) ? 2.0f : 1.0f;   // tanh for g-gate
    const float wo    = (l < 16) ? W_out[e] : 0.0f;
    const float bo    = b_out[0];

    float c1 = 0.f, c2 = 0.f;                      // live in lanes 0..15

    if (tid < HDIM) {
        ((uint32_t*)h1p)[tid] = 0u;                // both buffers
        ((uint32_t*)h2p)[tid] = 0u;
    }
    __syncthreads();

    const uint4* Wv = (const uint4*)wlds;
    const float* xb = x + b * T_STEPS;
    float*       ob = out + b * T_STEPS;
    float x_cur = xb[0];

    for (int t = 0; t < T_STEPS; t++) {
        const int rb = t & 1, wb = rb ^ 1;
        const uint4* Hv1R = (const uint4*)h1p[rb];
        const uint4* Hv2R = (const uint4*)h2p[rb];
        float x_nxt = xb[(t + 1 < T_STEPS) ? (t + 1) : t];

        // ---- phase 1: layer-1 gate row (register weights, broadcast h1_old)
        float aA = fmaf(x_cur, wih1, bias1), aB = 0.f;
        DOTQ4(w1_0, w1_1, w1_2, w1_3,  Hv1R, 0, aA);
        DOTQ4(w1_4, w1_5, w1_6, w1_7,  Hv1R, 1, aB); SB();
        DOTQ4(w1_8, w1_9, w1_10,w1_11, Hv1R, 2, aA);
        DOTQ4(w1_12,w1_13,w1_14,w1_15, Hv1R, 3, aB);
        float act1 = actf(aA + aB, mm);

        // ---- phase 2b: W_hh2 . h2_old (LDS weights; independent of layer 1,
        // issued here to cover act1/shuffle latency before update1)
        float qA = 0.f, qB = 0.f;
        uint4 U0,U1,U2,U3, V0,V1,V2,V3;
        LOADW(U0,U1,U2,U3, 0); SB();
        LOADW(V0,V1,V2,V3, 1); DOTQ4(U0,U1,U2,U3, Hv2R, 0, qA); SB();
        LOADW(U0,U1,U2,U3, 2); DOTQ4(V0,V1,V2,V3, Hv2R, 1, qB); SB();
        LOADW(V0,V1,V2,V3, 3); DOTQ4(U0,U1,U2,U3, Hv2R, 2, qA); SB();
        DOTQ4(V0,V1,V2,V3, Hv2R, 3, qB);

        // ---- layer-1 cell update: wave-local via shuffles
        {
            float f_ = __shfl_xor(act1, 16, 64);
            float g_ = __shfl_xor(act1, 32, 64);
            float o_ = __shfl_xor(act1, 48, 64);
            if (l < 16) {
                c1 = fmaf(f_, c1, act1 * g_);      // lane l holds gate i
                float h1 = o_ * actf(c1, 2.0f);    // tanh
                ((uint16_t*)h1p[wb])[e] = f2h(h1);
            }
        }
        __syncthreads();   // barrier A: h1_new published

        // ---- phase 2a: W_ih2 . h1_new (register weights)
        const uint4* Hv1W = (const uint4*)h1p[wb];
        DOTQ4(w2_0, w2_1, w2_2, w2_3,  Hv1W, 0, qA);
        DOTQ4(w2_4, w2_5, w2_6, w2_7,  Hv1W, 1, qB); SB();
        DOTQ4(w2_8, w2_9, w2_10,w2_11, Hv1W, 2, qA);
        DOTQ4(w2_12,w2_13,w2_14,w2_15, Hv1W, 3, qB);
        float act2 = actf((qA + qB) + bias2, mm);

        // ---- layer-2 cell update + in-wave output partial
        {
            float f_ = __shfl_xor(act2, 16, 64);
            float g_ = __shfl_xor(act2, 32, 64);
            float o_ = __shfl_xor(act2, 48, 64);
            if (l < 16) {
                c2 = fmaf(f_, c2, act2 * g_);
                float h2v = o_ * actf(c2, 2.0f);
                ((uint16_t*)h2p[wb])[e] = f2h(h2v);
                float part = wo * h2v;             // W_out . h2, 16 elems/wave
                part += __shfl_xor(part, 1, 64);
                part += __shfl_xor(part, 2, 64);
                part += __shfl_xor(part, 4, 64);
                part += __shfl_xor(part, 8, 64);
                if (l == 0) pbuf[w] = part;
            }
        }
        __syncthreads();   // barrier B: h2_new + partials published

        // ---- output: wave 0 sums 8 partials while others run ahead
        if (tid < 8) {
            float s = pbuf[tid];
            s += __shfl_xor(s, 1, 64);
            s += __shfl_xor(s, 2, 64);
            s += __shfl_xor(s, 4, 64);
            if (tid == 0) ob[t] = s + bo;
        }
        x_cur = x_nxt;
    }
}

extern "C" void kernel_launch(void* const* d_in, const int* in_sizes, int n_in,
                              void* d_out, int out_size, void* d_ws, size_t ws_size,
                              hipStream_t stream) {
    const float* x     = (const float*)d_in[0];
    const float* W_ih1 = (const float*)d_in[1];
    const float* W_hh1 = (const float*)d_in[2];
    const float* b_ih1 = (const float*)d_in[3];
    const float* b_hh1 = (const float*)d_in[4];
    const float* W_ih2 = (const float*)d_in[5];
    const float* W_hh2 = (const float*)d_in[6];
    const float* b_ih2 = (const float*)d_in[7];
    const float* b_hh2 = (const float*)d_in[8];
    const float* W_out = (const float*)d_in[9];
    const float* b_out = (const float*)d_in[10];
    float* out = (float*)d_out;

    const int B = in_sizes[0] / T_STEPS;   // 256
    hipLaunchKernelGGL(lstm_persistent, dim3(B), dim3(NT), 0, stream,
                       x, W_ih1, W_hh1, b_ih1, b_hh1,
                       W_ih2, W_hh2, b_ih2, b_hh2, W_out, b_out, out);
}

// Round 5
// 2256.058 us; speedup vs baseline: 1.9970x; 1.9970x over previous
//
#include <hip/hip_runtime.h>
#include <hip/hip_fp16.h>
#include <stdint.h>

#define T_STEPS 1024
#define HDIM    128
#define NT      1024

// Thread mapping (K-sliced design):
//   wave w = tid>>6, lane l = tid&63
//   slice  s  = l & 7      -> h columns [16s, 16s+16)
//   e_lo      = l >> 3
//   element e = 8w + e_lo  (0..127)
// Each thread holds the 16-column slice of ALL 4 gate rows of ALL 3 matrices
// (3*4*16 f16 = 96 VGPRs). Per matrix-phase it reads only its 32-byte h
// slice (2 ds_read_b128) and accumulates 4 gate partials; partials reduce
// over the 8 slice-lanes via xor1/2/4 (DPP quad-perm + 1 ds_swizzle).
// All lanes then hold all 4 gates of their element -> replicated cell
// update, no divergence, no gather. 2 barriers/step.
// Why: R0-R4 showed the compiler pins 512/1024-thread kernels at 128 VGPRs
// and spills anything bigger (WRITE_SIZE 28-74 MB, 2-4.5 ms); and the
// full-row design costs ~512 LDS instr/CU/step (LDS-pipe-bound). This
// design fits 128 by construction and cuts LDS instructions ~5x.

typedef _Float16 v2h __attribute__((ext_vector_type(2)));
union HU { uint32_t u; v2h v; };

__device__ __forceinline__ float dot2h(uint32_t a, uint32_t b, float c) {
    HU ua, ub; ua.u = a; ub.u = b;
    return __builtin_amdgcn_fdot2(ua.v, ub.v, c, false);  // v_dot2_f32_f16
}
__device__ __forceinline__ uint32_t packh2f(float2 e) {
    return (uint32_t)__half_as_ushort(__float2half_rn(e.x)) |
           ((uint32_t)__half_as_ushort(__float2half_rn(e.y)) << 16);
}
__device__ __forceinline__ uint16_t f2h(float f) {
    return __half_as_ushort(__float2half_rn(f));
}
// act(a,1)=sigmoid(a); act(a,2)=tanh(a)
__device__ __forceinline__ float actf(float a, float m) {
    return 1.0f - m * __builtin_amdgcn_rcpf(__expf(m * a) + 1.0f);
}

// reduce over the 8 slice-lanes (lane bits 0..2): xor1/xor2 as DPP
// quad-perm adds (VALU pipe, no LDS), xor4 as one ds_swizzle.
__device__ __forceinline__ float red3(float v) {
    int iv = __float_as_int(v);
    v += __int_as_float(__builtin_amdgcn_update_dpp(0, iv, 0xB1, 0xF, 0xF, true)); // quad_perm [1,0,3,2] = xor1
    iv = __float_as_int(v);
    v += __int_as_float(__builtin_amdgcn_update_dpp(0, iv, 0x4E, 0xF, 0xF, true)); // quad_perm [2,3,0,1] = xor2
    iv = __float_as_int(v);
    v += __int_as_float(__builtin_amdgcn_ds_swizzle(iv, 0x101F));                  // xor4
    return v;
}

#define SB() __builtin_amdgcn_sched_barrier(0)
#define PIN4(W) asm volatile("" : "+v"(W.x), "+v"(W.y), "+v"(W.z), "+v"(W.w))

// pack 16 consecutive floats at P into 2 uint4 of f16 pairs
#define SETW8(Wa, Wb, P) do { const float2* _r = (const float2*)(P);       \
    Wa = make_uint4(packh2f(_r[0]), packh2f(_r[1]),                        \
                    packh2f(_r[2]), packh2f(_r[3]));                       \
    Wb = make_uint4(packh2f(_r[4]), packh2f(_r[5]),                        \
                    packh2f(_r[6]), packh2f(_r[7])); } while (0)

// 8 dot2s: one gate-row slice (2 uint4) vs h slice (2 uint4)
#define DOT8(Wa, Wb, H0, H1, acc) do {                                     \
    acc = dot2h(Wa.x, H0.x, acc); acc = dot2h(Wa.y, H0.y, acc);            \
    acc = dot2h(Wa.z, H0.z, acc); acc = dot2h(Wa.w, H0.w, acc);            \
    acc = dot2h(Wb.x, H1.x, acc); acc = dot2h(Wb.y, H1.y, acc);            \
    acc = dot2h(Wb.z, H1.z, acc); acc = dot2h(Wb.w, H1.w, acc); } while (0)

__global__ __launch_bounds__(NT, 4) void lstm_persistent(
    const float* __restrict__ x,
    const float* __restrict__ W_ih1, const float* __restrict__ W_hh1,
    const float* __restrict__ b_ih1, const float* __restrict__ b_hh1,
    const float* __restrict__ W_ih2, const float* __restrict__ W_hh2,
    const float* __restrict__ b_ih2, const float* __restrict__ b_hh2,
    const float* __restrict__ W_out, const float* __restrict__ b_out,
    float* __restrict__ out)
{
    const int b   = blockIdx.x;
    const int tid = threadIdx.x;
    const int w   = tid >> 6;
    const int l   = tid & 63;
    const int s   = l & 7;
    const int e   = (w << 3) | (l >> 3);
    const int co  = s << 4;                       // column offset (floats)

    __shared__ __align__(16) uint32_t h1p[2][HDIM / 2];   // h1 f16 pairs, dbuf
    __shared__ __align__(16) uint32_t h2p[2][HDIM / 2];   // h2 f16 pairs, dbuf
    __shared__ __align__(16) float bc1[HDIM * 4];         // [e*4+g] b_ih1+b_hh1
    __shared__ __align__(16) float wx1[HDIM * 4];         // [e*4+g] W_ih1
    __shared__ __align__(16) float bc2[HDIM * 4];         // [e*4+g] b_ih2+b_hh2
    __shared__ float pbuf[16];                            // per-wave out partials

    // ---- one-time: weight slices -> 24 named uint4 (96 VGPRs)
    uint4 m1_0a,m1_0b,m1_1a,m1_1b,m1_2a,m1_2b,m1_3a,m1_3b;   // W_hh1
    uint4 m2_0a,m2_0b,m2_1a,m2_1b,m2_2a,m2_2b,m2_3a,m2_3b;   // W_ih2
    uint4 m3_0a,m3_0b,m3_1a,m3_1b,m3_2a,m3_2b,m3_3a,m3_3b;   // W_hh2
    {
        const float* p1 = W_hh1 + e * HDIM + co;   // row g*128+e, cols [co,co+16)
        SETW8(m1_0a, m1_0b, p1);
        SETW8(m1_1a, m1_1b, p1 + 128 * HDIM);
        SETW8(m1_2a, m1_2b, p1 + 256 * HDIM);
        SETW8(m1_3a, m1_3b, p1 + 384 * HDIM);
        const float* p2 = W_ih2 + e * HDIM + co;
        SETW8(m2_0a, m2_0b, p2);
        SETW8(m2_1a, m2_1b, p2 + 128 * HDIM);
        SETW8(m2_2a, m2_2b, p2 + 256 * HDIM);
        SETW8(m2_3a, m2_3b, p2 + 384 * HDIM);
        const float* p3 = W_hh2 + e * HDIM + co;
        SETW8(m3_0a, m3_0b, p3);
        SETW8(m3_1a, m3_1b, p3 + 128 * HDIM);
        SETW8(m3_2a, m3_2b, p3 + 256 * HDIM);
        SETW8(m3_3a, m3_3b, p3 + 384 * HDIM);
    }
    PIN4(m1_0a); PIN4(m1_0b); PIN4(m1_1a); PIN4(m1_1b);
    PIN4(m1_2a); PIN4(m1_2b); PIN4(m1_3a); PIN4(m1_3b);
    PIN4(m2_0a); PIN4(m2_0b); PIN4(m2_1a); PIN4(m2_1b);
    PIN4(m2_2a); PIN4(m2_2b); PIN4(m2_3a); PIN4(m2_3b);
    PIN4(m3_0a); PIN4(m3_0b); PIN4(m3_1a); PIN4(m3_1b);
    PIN4(m3_2a); PIN4(m3_2b); PIN4(m3_3a); PIN4(m3_3b);

    // ---- one-time: bias / x-weight tables ([e][4] float4-readable)
    if (tid < 512) {
        int ee = tid >> 2, g = tid & 3, row = g * HDIM + ee;
        bc1[tid] = b_ih1[row] + b_hh1[row];
        wx1[tid] = W_ih1[row];
        bc2[tid] = b_ih2[row] + b_hh2[row];
    }
    const float wo = (s == 0) ? W_out[e] : 0.0f;   // zero on non-s0 lanes
    const float bo = b_out[0];

    float c1 = 0.f, c2 = 0.f;                      // replicated across 8 lanes

    if (tid < HDIM / 2) {
        h1p[0][tid] = 0u; h1p[1][tid] = 0u;
        h2p[0][tid] = 0u; h2p[1][tid] = 0u;
    }
    __syncthreads();

    const float* xb = x + b * T_STEPS;
    float*       ob = out + b * T_STEPS;

    for (int t = 0; t < T_STEPS; t++) {
        const int rb = t & 1, wb2 = rb ^ 1;

        // uniform x -> SGPR (saves a VGPR, broadcast operand is free)
        float x_cur = __int_as_float(
            __builtin_amdgcn_readfirstlane(__float_as_int(xb[t])));

        // ---- phase 1: layer-1 partials over slice s (32 dot2, 4 chains)
        float a0 = 0.f, a1 = 0.f, a2 = 0.f, a3 = 0.f;
        {
            const uint4* H = (const uint4*)h1p[rb];
            uint4 H0 = H[2 * s], H1 = H[2 * s + 1];
            DOT8(m1_0a, m1_0b, H0, H1, a0);
            DOT8(m1_1a, m1_1b, H0, H1, a1);
            DOT8(m1_2a, m1_2b, H0, H1, a2);
            DOT8(m1_3a, m1_3b, H0, H1, a3);
        }
        SB();
        // bias reads: opaque index so they stay IN the loop (12 transient
        // regs here instead of 12 persistent ones)
        int eb = e * 16;
        asm volatile("" : "+v"(eb));
        float4 B1 = *(const float4*)((const char*)bc1 + eb);
        float4 Wx = *(const float4*)((const char*)wx1 + eb);
        a0 = red3(a0); a1 = red3(a1); a2 = red3(a2); a3 = red3(a3);
        float gi = actf(a0 + fmaf(x_cur, Wx.x, B1.x), 1.0f);
        float gf = actf(a1 + fmaf(x_cur, Wx.y, B1.y), 1.0f);
        float gg = actf(a2 + fmaf(x_cur, Wx.z, B1.z), 2.0f);
        float go = actf(a3 + fmaf(x_cur, Wx.w, B1.w), 1.0f);
        c1 = fmaf(gf, c1, gi * gg);
        float h1 = go * actf(c1, 2.0f);
        if (s == 0) ((uint16_t*)h1p[wb2])[e] = f2h(h1);
        __syncthreads();   // barrier A: h1_new published

        // ---- phase 2: layer-2 partials = W_ih2.h1_new + W_hh2.h2_old
        float q0 = 0.f, q1 = 0.f, q2 = 0.f, q3 = 0.f;
        {
            const uint4* Hn = (const uint4*)h1p[wb2];
            uint4 H0 = Hn[2 * s], H1 = Hn[2 * s + 1];
            DOT8(m2_0a, m2_0b, H0, H1, q0);
            DOT8(m2_1a, m2_1b, H0, H1, q1);
            DOT8(m2_2a, m2_2b, H0, H1, q2);
            DOT8(m2_3a, m2_3b, H0, H1, q3);
        }
        SB();
        {
            const uint4* Ho = (const uint4*)h2p[rb];
            uint4 G0 = Ho[2 * s], G1 = Ho[2 * s + 1];
            DOT8(m3_0a, m3_0b, G0, G1, q0);
            DOT8(m3_1a, m3_1b, G0, G1, q1);
            DOT8(m3_2a, m3_2b, G0, G1, q2);
            DOT8(m3_3a, m3_3b, G0, G1, q3);
        }
        SB();
        int eb2 = e * 16;
        asm volatile("" : "+v"(eb2));
        float4 B2 = *(const float4*)((const char*)bc2 + eb2);
        q0 = red3(q0); q1 = red3(q1); q2 = red3(q2); q3 = red3(q3);
        float hi = actf(q0 + B2.x, 1.0f);
        float hf = actf(q1 + B2.y, 1.0f);
        float hg = actf(q2 + B2.z, 2.0f);
        float ho = actf(q3 + B2.w, 1.0f);
        c2 = fmaf(hf, c2, hi * hg);
        float h2v = ho * actf(c2, 2.0f);
        if (s == 0) ((uint16_t*)h2p[wb2])[e] = f2h(h2v);

        // output partial: wo is 0 on s!=0 lanes; sum the 8 elements of this
        // wave (lane bits 3..5) onto lane 0
        float part = wo * h2v;
        part += __shfl_xor(part, 8,  64);
        part += __shfl_xor(part, 16, 64);
        part += __shfl_xor(part, 32, 64);
        if (l == 0) pbuf[w] = part;
        __syncthreads();   // barrier B: h2_new + partials published

        // ---- output: wave 0 sums 16 wave-partials while others run ahead
        if (tid < 16) {
            float ssum = pbuf[tid];
            ssum += __shfl_xor(ssum, 1, 64);
            ssum += __shfl_xor(ssum, 2, 64);
            ssum += __shfl_xor(ssum, 4, 64);
            ssum += __shfl_xor(ssum, 8, 64);
            if (tid == 0) ob[t] = ssum + bo;
        }
    }
}

extern "C" void kernel_launch(void* const* d_in, const int* in_sizes, int n_in,
                              void* d_out, int out_size, void* d_ws, size_t ws_size,
                              hipStream_t stream) {
    const float* x     = (const float*)d_in[0];
    const float* W_ih1 = (const float*)d_in[1];
    const float* W_hh1 = (const float*)d_in[2];
    const float* b_ih1 = (const float*)d_in[3];
    const float* b_hh1 = (const float*)d_in[4];
    const float* W_ih2 = (const float*)d_in[5];
    const float* W_hh2 = (const float*)d_in[6];
    const float* b_ih2 = (const float*)d_in[7];
    const float* b_hh2 = (const float*)d_in[8];
    const float* W_out = (const float*)d_in[9];
    const float* b_out = (const float*)d_in[10];
    float* out = (float*)d_out;

    const int B = in_sizes[0] / T_STEPS;   // 256
    hipLaunchKernelGGL(lstm_persistent, dim3(B), dim3(NT), 0, stream,
                       x, W_ih1, W_hh1, b_ih1, b_hh1,
                       W_ih2, W_hh2, b_ih2, b_hh2, W_out, b_out, out);
}

// Round 6
// 1699.070 us; speedup vs baseline: 2.6516x; 1.3278x over previous
//
#include <hip/hip_runtime.h>
#include <hip/hip_fp16.h>
#include <stdint.h>

#define T_STEPS 1024
#define HDIM    128
#define NT      512

// K-sliced design, slice = 4 (R6):
//   wave w = tid>>6 (0..7), lane l = tid&63
//   slice   s = l & 3        -> h columns [32s, 32s+32)
//   element e = 16w + (l>>2) (0..127)
// Each thread holds the 32-column slice of all 4 gate rows of all 3
// matrices: 3*4*32 f16 = 192 VGPRs, plus 12 bias regs -> needs the full
// 256-reg file. amdgpu_waves_per_eu(2,2) pins the allocator's occupancy
// target at 2 waves/EU (= the real occupancy: one 8-wave block/CU) so it
// actually allocates 256 instead of targeting 4 waves and spilling/AGPRing
// (the failure mode of R0/R2/R4; R5's NT=1024 hard-capped at 128).
// Gate partials reduce over the 4 slice-lanes with two DPP quad-perm adds
// (pure VALU, no ds_swizzle). All lanes then hold all 4 gates of their
// element -> replicated cell update, no divergence. 2 barriers/step.

typedef _Float16 v2h __attribute__((ext_vector_type(2)));
union HU { uint32_t u; v2h v; };

__device__ __forceinline__ float dot2h(uint32_t a, uint32_t b, float c) {
    HU ua, ub; ua.u = a; ub.u = b;
    return __builtin_amdgcn_fdot2(ua.v, ub.v, c, false);  // v_dot2_f32_f16
}
__device__ __forceinline__ uint32_t packh2f(float2 e) {
    return (uint32_t)__half_as_ushort(__float2half_rn(e.x)) |
           ((uint32_t)__half_as_ushort(__float2half_rn(e.y)) << 16);
}
__device__ __forceinline__ uint16_t f2h(float f) {
    return __half_as_ushort(__float2half_rn(f));
}
// act(a,1)=sigmoid(a); act(a,2)=tanh(a)
__device__ __forceinline__ float actf(float a, float m) {
    return 1.0f - m * __builtin_amdgcn_rcpf(__expf(m * a) + 1.0f);
}

// reduce over the 4 slice-lanes (lane bits 0..1): two DPP quad-perm adds.
__device__ __forceinline__ float red2(float v) {
    int iv = __float_as_int(v);
    v += __int_as_float(__builtin_amdgcn_update_dpp(0, iv, 0xB1, 0xF, 0xF, true)); // [1,0,3,2] xor1
    iv = __float_as_int(v);
    v += __int_as_float(__builtin_amdgcn_update_dpp(0, iv, 0x4E, 0xF, 0xF, true)); // [2,3,0,1] xor2
    return v;
}

#define SB() __builtin_amdgcn_sched_barrier(0)
#define PIN4(W) asm volatile("" : "+v"(W.x), "+v"(W.y), "+v"(W.z), "+v"(W.w))

// pack 32 consecutive floats at P into 4 uint4 of f16 pairs
#define SETW16(Wa, Wb, Wc, Wd, P) do { const float2* _r = (const float2*)(P); \
    Wa = make_uint4(packh2f(_r[0]),  packh2f(_r[1]),                       \
                    packh2f(_r[2]),  packh2f(_r[3]));                      \
    Wb = make_uint4(packh2f(_r[4]),  packh2f(_r[5]),                       \
                    packh2f(_r[6]),  packh2f(_r[7]));                      \
    Wc = make_uint4(packh2f(_r[8]),  packh2f(_r[9]),                       \
                    packh2f(_r[10]), packh2f(_r[11]));                     \
    Wd = make_uint4(packh2f(_r[12]), packh2f(_r[13]),                      \
                    packh2f(_r[14]), packh2f(_r[15])); } while (0)

// 8 dot2s: one weight pair (2 uint4 = 16 cols) vs h pair
#define DOT8(Wa, Wb, H0, H1, acc) do {                                     \
    acc = dot2h(Wa.x, H0.x, acc); acc = dot2h(Wa.y, H0.y, acc);            \
    acc = dot2h(Wa.z, H0.z, acc); acc = dot2h(Wa.w, H0.w, acc);            \
    acc = dot2h(Wb.x, H1.x, acc); acc = dot2h(Wb.y, H1.y, acc);            \
    acc = dot2h(Wb.z, H1.z, acc); acc = dot2h(Wb.w, H1.w, acc); } while (0)

// 16 dot2s: full 32-col slice of one gate row vs h slice (4 uint4)
#define DOT16(W0, W1, W2, W3, H0, H1, H2, H3, acc) do {                    \
    DOT8(W0, W1, H0, H1, acc); DOT8(W2, W3, H2, H3, acc); } while (0)

__global__ __launch_bounds__(NT)
__attribute__((amdgpu_waves_per_eu(2, 2)))
void lstm_persistent(
    const float* __restrict__ x,
    const float* __restrict__ W_ih1, const float* __restrict__ W_hh1,
    const float* __restrict__ b_ih1, const float* __restrict__ b_hh1,
    const float* __restrict__ W_ih2, const float* __restrict__ W_hh2,
    const float* __restrict__ b_ih2, const float* __restrict__ b_hh2,
    const float* __restrict__ W_out, const float* __restrict__ b_out,
    float* __restrict__ out)
{
    const int b   = blockIdx.x;
    const int tid = threadIdx.x;
    const int w   = tid >> 6;
    const int l   = tid & 63;
    const int s   = l & 3;
    const int e   = (w << 4) | (l >> 2);
    const int co  = s << 5;                       // column offset (floats)

    __shared__ __align__(16) uint32_t h1p[2][HDIM / 2];   // h1 f16 pairs, dbuf
    __shared__ __align__(16) uint32_t h2p[2][HDIM / 2];   // h2 f16 pairs, dbuf
    __shared__ float pbuf[8];                             // per-wave out partials

    // ---- one-time: weight slices -> 48 named uint4 (192 VGPRs)
    uint4 m1_00,m1_01,m1_02,m1_03, m1_10,m1_11,m1_12,m1_13;   // W_hh1 gates i,f
    uint4 m1_20,m1_21,m1_22,m1_23, m1_30,m1_31,m1_32,m1_33;   //        g,o
    uint4 m2_00,m2_01,m2_02,m2_03, m2_10,m2_11,m2_12,m2_13;   // W_ih2
    uint4 m2_20,m2_21,m2_22,m2_23, m2_30,m2_31,m2_32,m2_33;
    uint4 m3_00,m3_01,m3_02,m3_03, m3_10,m3_11,m3_12,m3_13;   // W_hh2
    uint4 m3_20,m3_21,m3_22,m3_23, m3_30,m3_31,m3_32,m3_33;
    {
        const float* p = W_hh1 + e * HDIM + co;   // row g*128+e, cols [co,co+32)
        SETW16(m1_00,m1_01,m1_02,m1_03, p);
        SETW16(m1_10,m1_11,m1_12,m1_13, p + 128 * HDIM);
        SETW16(m1_20,m1_21,m1_22,m1_23, p + 256 * HDIM);
        SETW16(m1_30,m1_31,m1_32,m1_33, p + 384 * HDIM);
        p = W_ih2 + e * HDIM + co;
        SETW16(m2_00,m2_01,m2_02,m2_03, p);
        SETW16(m2_10,m2_11,m2_12,m2_13, p + 128 * HDIM);
        SETW16(m2_20,m2_21,m2_22,m2_23, p + 256 * HDIM);
        SETW16(m2_30,m2_31,m2_32,m2_33, p + 384 * HDIM);
        p = W_hh2 + e * HDIM + co;
        SETW16(m3_00,m3_01,m3_02,m3_03, p);
        SETW16(m3_10,m3_11,m3_12,m3_13, p + 128 * HDIM);
        SETW16(m3_20,m3_21,m3_22,m3_23, p + 256 * HDIM);
        SETW16(m3_30,m3_31,m3_32,m3_33, p + 384 * HDIM);
    }
    PIN4(m1_00); PIN4(m1_01); PIN4(m1_02); PIN4(m1_03);
    PIN4(m1_10); PIN4(m1_11); PIN4(m1_12); PIN4(m1_13);
    PIN4(m1_20); PIN4(m1_21); PIN4(m1_22); PIN4(m1_23);
    PIN4(m1_30); PIN4(m1_31); PIN4(m1_32); PIN4(m1_33);
    PIN4(m2_00); PIN4(m2_01); PIN4(m2_02); PIN4(m2_03);
    PIN4(m2_10); PIN4(m2_11); PIN4(m2_12); PIN4(m2_13);
    PIN4(m2_20); PIN4(m2_21); PIN4(m2_22); PIN4(m2_23);
    PIN4(m2_30); PIN4(m2_31); PIN4(m2_32); PIN4(m2_33);
    PIN4(m3_00); PIN4(m3_01); PIN4(m3_02); PIN4(m3_03);
    PIN4(m3_10); PIN4(m3_11); PIN4(m3_12); PIN4(m3_13);
    PIN4(m3_20); PIN4(m3_21); PIN4(m3_22); PIN4(m3_23);
    PIN4(m3_30); PIN4(m3_31); PIN4(m3_32); PIN4(m3_33);

    // ---- one-time: biases / x-weights in registers (12 + 2)
    const float b1i = b_ih1[e]       + b_hh1[e];
    const float b1f = b_ih1[e + 128] + b_hh1[e + 128];
    const float b1g = b_ih1[e + 256] + b_hh1[e + 256];
    const float b1o = b_ih1[e + 384] + b_hh1[e + 384];
    const float wxi = W_ih1[e],      wxf = W_ih1[e + 128];
    const float wxg = W_ih1[e + 256], wxo = W_ih1[e + 384];
    const float b2i = b_ih2[e]       + b_hh2[e];
    const float b2f = b_ih2[e + 128] + b_hh2[e + 128];
    const float b2g = b_ih2[e + 256] + b_hh2[e + 256];
    const float b2o = b_ih2[e + 384] + b_hh2[e + 384];
    const float wo  = (s == 0) ? W_out[e] : 0.0f;
    const float bo  = b_out[0];

    float c1 = 0.f, c2 = 0.f;                      // replicated across 4 lanes

    if (tid < HDIM / 2) {
        h1p[0][tid] = 0u; h1p[1][tid] = 0u;
        h2p[0][tid] = 0u; h2p[1][tid] = 0u;
    }
    __syncthreads();

    const float* xb = x + b * T_STEPS;
    float*       ob = out + b * T_STEPS;
    float x_cur = xb[0];

    for (int t = 0; t < T_STEPS; t++) {
        const int rb = t & 1, wb2 = rb ^ 1;
        // prefetch next x (off the critical path; consumed next iteration)
        float x_nxt = xb[(t + 1 < T_STEPS) ? (t + 1) : t];

        // ---- phase 1: layer-1 partials over slice s (64 dot2, 4 chains)
        float a0 = 0.f, a1 = 0.f, a2 = 0.f, a3 = 0.f;
        {
            const uint4* H = (const uint4*)h1p[rb];
            uint4 H0 = H[4*s], H1 = H[4*s+1], H2 = H[4*s+2], H3 = H[4*s+3];
            DOT16(m1_00,m1_01,m1_02,m1_03, H0,H1,H2,H3, a0);
            DOT16(m1_10,m1_11,m1_12,m1_13, H0,H1,H2,H3, a1);
            DOT16(m1_20,m1_21,m1_22,m1_23, H0,H1,H2,H3, a2);
            DOT16(m1_30,m1_31,m1_32,m1_33, H0,H1,H2,H3, a3);
        }
        a0 = red2(a0); a1 = red2(a1); a2 = red2(a2); a3 = red2(a3);
        float gi = actf(a0 + fmaf(x_cur, wxi, b1i), 1.0f);
        float gf = actf(a1 + fmaf(x_cur, wxf, b1f), 1.0f);
        float gg = actf(a2 + fmaf(x_cur, wxg, b1g), 2.0f);
        float go = actf(a3 + fmaf(x_cur, wxo, b1o), 1.0f);
        c1 = fmaf(gf, c1, gi * gg);
        float h1 = go * actf(c1, 2.0f);
        if (s == 0) ((uint16_t*)h1p[wb2])[e] = f2h(h1);
        __syncthreads();   // barrier A: h1_new published

        // ---- phase 2: layer-2 partials = W_ih2.h1_new + W_hh2.h2_old
        float q0 = 0.f, q1 = 0.f, q2 = 0.f, q3 = 0.f;
        {
            const uint4* Hn = (const uint4*)h1p[wb2];
            uint4 G0 = Hn[4*s], G1 = Hn[4*s+1], G2 = Hn[4*s+2], G3 = Hn[4*s+3];
            DOT16(m2_00,m2_01,m2_02,m2_03, G0,G1,G2,G3, q0);
            DOT16(m2_10,m2_11,m2_12,m2_13, G0,G1,G2,G3, q1);
            DOT16(m2_20,m2_21,m2_22,m2_23, G0,G1,G2,G3, q2);
            DOT16(m2_30,m2_31,m2_32,m2_33, G0,G1,G2,G3, q3);
        }
        SB();   // fence: keep h2_old temps from overlapping the block above
        {
            const uint4* Ho = (const uint4*)h2p[rb];
            uint4 G0 = Ho[4*s], G1 = Ho[4*s+1], G2 = Ho[4*s+2], G3 = Ho[4*s+3];
            DOT16(m3_00,m3_01,m3_02,m3_03, G0,G1,G2,G3, q0);
            DOT16(m3_10,m3_11,m3_12,m3_13, G0,G1,G2,G3, q1);
            DOT16(m3_20,m3_21,m3_22,m3_23, G0,G1,G2,G3, q2);
            DOT16(m3_30,m3_31,m3_32,m3_33, G0,G1,G2,G3, q3);
        }
        q0 = red2(q0); q1 = red2(q1); q2 = red2(q2); q3 = red2(q3);
        float hi = actf(q0 + b2i, 1.0f);
        float hf = actf(q1 + b2f, 1.0f);
        float hg = actf(q2 + b2g, 2.0f);
        float ho = actf(q3 + b2o, 1.0f);
        c2 = fmaf(hf, c2, hi * hg);
        float h2v = ho * actf(c2, 2.0f);
        if (s == 0) ((uint16_t*)h2p[wb2])[e] = f2h(h2v);

        // output partial: wo is 0 on s!=0 lanes; reduce this wave's 16
        // elements (lane bits 2..5) onto lane 0
        float part = wo * h2v;
        part += __shfl_xor(part, 4,  64);
        part += __shfl_xor(part, 8,  64);
        part += __shfl_xor(part, 16, 64);
        part += __shfl_xor(part, 32, 64);
        if (l == 0) pbuf[w] = part;
        __syncthreads();   // barrier B: h2_new + partials published

        // ---- output: wave 0 sums 8 wave-partials while others run ahead
        if (tid < 8) {
            float ssum = pbuf[tid];
            ssum += __shfl_xor(ssum, 1, 64);
            ssum += __shfl_xor(ssum, 2, 64);
            ssum += __shfl_xor(ssum, 4, 64);
            if (tid == 0) ob[t] = ssum + bo;
        }
        x_cur = x_nxt;
    }
}

extern "C" void kernel_launch(void* const* d_in, const int* in_sizes, int n_in,
                              void* d_out, int out_size, void* d_ws, size_t ws_size,
                              hipStream_t stream) {
    const float* x     = (const float*)d_in[0];
    const float* W_ih1 = (const float*)d_in[1];
    const float* W_hh1 = (const float*)d_in[2];
    const float* b_ih1 = (const float*)d_in[3];
    const float* b_hh1 = (const float*)d_in[4];
    const float* W_ih2 = (const float*)d_in[5];
    const float* W_hh2 = (const float*)d_in[6];
    const float* b_ih2 = (const float*)d_in[7];
    const float* b_hh2 = (const float*)d_in[8];
    const float* W_out = (const float*)d_in[9];
    const float* b_out = (const float*)d_in[10];
    float* out = (float*)d_out;

    const int B = in_sizes[0] / T_STEPS;   // 256
    hipLaunchKernelGGL(lstm_persistent, dim3(B), dim3(NT), 0, stream,
                       x, W_ih1, W_hh1, b_ih1, b_hh1,
                       W_ih2, W_hh2, b_ih2, b_hh2, W_out, b_out, out);
}

// Round 7
// 1589.462 us; speedup vs baseline: 2.8345x; 1.0690x over previous
//
#include <hip/hip_runtime.h>
#include <hip/hip_fp16.h>
#include <stdint.h>

#define T_STEPS 1024
#define HDIM    128
#define NT      512

// K-sliced, single-barrier pipelined design (R7):
//   wave w = tid>>6 (0..7), lane l = tid&63
//   slice   s = l & 3        -> h columns [32s, 32s+32)
//   element e = 16w + (l>>2) (0..127)
// Iteration k fuses: gates1(k)   = W_hh1*h1(k-1)            (+ x(k), bias)
//                    gates2(k-1) = W_ih2*h1(k-1) + W_hh2*h2(k-2)
// Both read the SAME published state -> one 192-dot block (8 indep acc
// chains), two independent epilogues, ONE barrier publishing {h1(k),
// h2(k-1)}. out(k-1) partials go to pbuf, summed+stored next iteration.
// Barriers/step: 2 -> 1; h1 read once not twice (12 -> 8 ds_read_b128).
// R6 lesson: VGPR_Count=124 meant the allocator exiled the 192 weight
// dwords to AGPRs (v_accvgpr_read per dot2, ~1100 cyc/SIMD/step) because
// the UNFENCED init hoisted 12 rows x 32 load-dwords -> >350 live at one
// point -> global alloc decision. Fix: SB() fence after each row pack.

typedef _Float16 v2h __attribute__((ext_vector_type(2)));
union HU { uint32_t u; v2h v; };

__device__ __forceinline__ float dot2h(uint32_t a, uint32_t b, float c) {
    HU ua, ub; ua.u = a; ub.u = b;
    return __builtin_amdgcn_fdot2(ua.v, ub.v, c, false);  // v_dot2_f32_f16
}
__device__ __forceinline__ uint32_t packh2f(float2 e) {
    return (uint32_t)__half_as_ushort(__float2half_rn(e.x)) |
           ((uint32_t)__half_as_ushort(__float2half_rn(e.y)) << 16);
}
__device__ __forceinline__ uint16_t f2h(float f) {
    return __half_as_ushort(__float2half_rn(f));
}
// act(a,1)=sigmoid(a); act(a,2)=tanh(a)
__device__ __forceinline__ float actf(float a, float m) {
    return 1.0f - m * __builtin_amdgcn_rcpf(__expf(m * a) + 1.0f);
}
// reduce over the 4 slice-lanes (lane bits 0..1): two DPP quad-perm adds.
__device__ __forceinline__ float red2(float v) {
    int iv = __float_as_int(v);
    v += __int_as_float(__builtin_amdgcn_update_dpp(0, iv, 0xB1, 0xF, 0xF, true)); // xor1
    iv = __float_as_int(v);
    v += __int_as_float(__builtin_amdgcn_update_dpp(0, iv, 0x4E, 0xF, 0xF, true)); // xor2
    return v;
}

#define SB() __builtin_amdgcn_sched_barrier(0)
#define PIN4(W) asm volatile("" : "+v"(W.x), "+v"(W.y), "+v"(W.z), "+v"(W.w))

// pack 32 consecutive floats at P into 4 uint4 of f16 pairs
#define SETW16(Wa, Wb, Wc, Wd, P) do { const float2* _r = (const float2*)(P); \
    Wa = make_uint4(packh2f(_r[0]),  packh2f(_r[1]),                       \
                    packh2f(_r[2]),  packh2f(_r[3]));                      \
    Wb = make_uint4(packh2f(_r[4]),  packh2f(_r[5]),                       \
                    packh2f(_r[6]),  packh2f(_r[7]));                      \
    Wc = make_uint4(packh2f(_r[8]),  packh2f(_r[9]),                       \
                    packh2f(_r[10]), packh2f(_r[11]));                     \
    Wd = make_uint4(packh2f(_r[12]), packh2f(_r[13]),                      \
                    packh2f(_r[14]), packh2f(_r[15])); } while (0)

// row pack + immediate pin + scheduling fence: caps init register-pressure
// spike at ~32 transient dwords per row.
#define ROW(Wa, Wb, Wc, Wd, P) do {                                        \
    SETW16(Wa, Wb, Wc, Wd, P);                                             \
    PIN4(Wa); PIN4(Wb); PIN4(Wc); PIN4(Wd); SB(); } while (0)

// 8 dot2s: one weight pair (2 uint4 = 16 cols) vs h pair
#define DOT8(Wa, Wb, H0, H1, acc) do {                                     \
    acc = dot2h(Wa.x, H0.x, acc); acc = dot2h(Wa.y, H0.y, acc);            \
    acc = dot2h(Wa.z, H0.z, acc); acc = dot2h(Wa.w, H0.w, acc);            \
    acc = dot2h(Wb.x, H1.x, acc); acc = dot2h(Wb.y, H1.y, acc);            \
    acc = dot2h(Wb.z, H1.z, acc); acc = dot2h(Wb.w, H1.w, acc); } while (0)

__global__ __launch_bounds__(NT)
__attribute__((amdgpu_waves_per_eu(2, 2)))
void lstm_persistent(
    const float* __restrict__ x,
    const float* __restrict__ W_ih1, const float* __restrict__ W_hh1,
    const float* __restrict__ b_ih1, const float* __restrict__ b_hh1,
    const float* __restrict__ W_ih2, const float* __restrict__ W_hh2,
    const float* __restrict__ b_ih2, const float* __restrict__ b_hh2,
    const float* __restrict__ W_out, const float* __restrict__ b_out,
    float* __restrict__ out)
{
    const int b   = blockIdx.x;
    const int tid = threadIdx.x;
    const int w   = tid >> 6;
    const int l   = tid & 63;
    const int s   = l & 3;
    const int e   = (w << 4) | (l >> 2);
    const int co  = s << 5;                       // column offset (floats)

    __shared__ __align__(16) uint32_t h1p[2][HDIM / 2];   // h1 f16 pairs, dbuf
    __shared__ __align__(16) uint32_t h2p[2][HDIM / 2];   // h2 f16 pairs, dbuf
    __shared__ __align__(16) float4 bct1[HDIM];   // per-element L1 biases (i,f,g,o)
    __shared__ __align__(16) float4 bctw[HDIM];   // per-element W_ih1    (i,f,g,o)
    __shared__ __align__(16) float4 bct2[HDIM];   // per-element L2 biases
    __shared__ float pbuf[2][8];                  // per-wave out partials, dbuf

    // ---- one-time: weight slices -> 48 named uint4 (192 VGPRs), fenced
    uint4 m1_00,m1_01,m1_02,m1_03, m1_10,m1_11,m1_12,m1_13;   // W_hh1
    uint4 m1_20,m1_21,m1_22,m1_23, m1_30,m1_31,m1_32,m1_33;
    uint4 m2_00,m2_01,m2_02,m2_03, m2_10,m2_11,m2_12,m2_13;   // W_ih2
    uint4 m2_20,m2_21,m2_22,m2_23, m2_30,m2_31,m2_32,m2_33;
    uint4 m3_00,m3_01,m3_02,m3_03, m3_10,m3_11,m3_12,m3_13;   // W_hh2
    uint4 m3_20,m3_21,m3_22,m3_23, m3_30,m3_31,m3_32,m3_33;
    {
        const float* p = W_hh1 + e * HDIM + co;
        ROW(m1_00,m1_01,m1_02,m1_03, p);
        ROW(m1_10,m1_11,m1_12,m1_13, p + 128 * HDIM);
        ROW(m1_20,m1_21,m1_22,m1_23, p + 256 * HDIM);
        ROW(m1_30,m1_31,m1_32,m1_33, p + 384 * HDIM);
        p = W_ih2 + e * HDIM + co;
        ROW(m2_00,m2_01,m2_02,m2_03, p);
        ROW(m2_10,m2_11,m2_12,m2_13, p + 128 * HDIM);
        ROW(m2_20,m2_21,m2_22,m2_23, p + 256 * HDIM);
        ROW(m2_30,m2_31,m2_32,m2_33, p + 384 * HDIM);
        p = W_hh2 + e * HDIM + co;
        ROW(m3_00,m3_01,m3_02,m3_03, p);
        ROW(m3_10,m3_11,m3_12,m3_13, p + 128 * HDIM);
        ROW(m3_20,m3_21,m3_22,m3_23, p + 256 * HDIM);
        ROW(m3_30,m3_31,m3_32,m3_33, p + 384 * HDIM);
    }

    // ---- one-time: bias / x-weight tables in LDS (keeps them out of the
    // persistent register set; read per-step with an opaque index)
    if (tid < HDIM) {
        bct1[tid] = make_float4(
            b_ih1[tid]       + b_hh1[tid],
            b_ih1[tid + 128] + b_hh1[tid + 128],
            b_ih1[tid + 256] + b_hh1[tid + 256],
            b_ih1[tid + 384] + b_hh1[tid + 384]);
        bctw[tid] = make_float4(W_ih1[tid], W_ih1[tid + 128],
                                W_ih1[tid + 256], W_ih1[tid + 384]);
        bct2[tid] = make_float4(
            b_ih2[tid]       + b_hh2[tid],
            b_ih2[tid + 128] + b_hh2[tid + 128],
            b_ih2[tid + 256] + b_hh2[tid + 256],
            b_ih2[tid + 384] + b_hh2[tid + 384]);
    }
    const float wo = (s == 0) ? W_out[e] : 0.0f;
    const float bo = b_out[0];

    float c1 = 0.f, c2 = 0.f;                      // replicated across 4 lanes

    if (tid < HDIM / 2) {
        h1p[0][tid] = 0u; h1p[1][tid] = 0u;        // h1(-1) = h2(-1) = 0
        h2p[0][tid] = 0u; h2p[1][tid] = 0u;
    }
    __syncthreads();

    const float* xb = x + b * T_STEPS;
    float*       ob = out + b * T_STEPS;
    float x_cur = xb[0];

    // Iteration k (k = 0..T): computes h1(k) and h2(k-1)/out(k-1).
    for (int k = 0; k <= T_STEPS; ++k) {
        const int rb = k & 1, wbuf = rb ^ 1;
        float x_nxt = xb[(k + 1 < T_STEPS) ? (k + 1) : (T_STEPS - 1)];

        // ---- store out(k-2): partials were published before last barrier
        if (k >= 2 && tid < 8) {
            float ssum = pbuf[wbuf][tid];
            ssum += __shfl_xor(ssum, 1, 64);
            ssum += __shfl_xor(ssum, 2, 64);
            ssum += __shfl_xor(ssum, 4, 64);
            if (tid == 0) ob[k - 2] = ssum + bo;
        }

        // ---- fused dot block: 192 dot2, 8 independent acc chains.
        // h1(k-1) read ONCE, feeds both m1 (gates1) and m2 (gates2).
        const uint4* H1 = (const uint4*)h1p[rb];
        const uint4* H2 = (const uint4*)h2p[rb];
        uint4 Ha0 = H1[4*s+0], Ha1 = H1[4*s+1];   // h1 cols [co, co+16)
        uint4 Hb0 = H1[4*s+2], Hb1 = H1[4*s+3];   // h1 cols [co+16, co+32)
        uint4 Hc0 = H2[4*s+0], Hc1 = H2[4*s+1];   // h2 halves
        uint4 Hd0 = H2[4*s+2], Hd1 = H2[4*s+3];
        float a0=0.f,a1=0.f,a2=0.f,a3=0.f, q0=0.f,q1=0.f,q2=0.f,q3=0.f;
        DOT8(m1_00,m1_01, Ha0,Ha1, a0); DOT8(m1_10,m1_11, Ha0,Ha1, a1);
        DOT8(m1_20,m1_21, Ha0,Ha1, a2); DOT8(m1_30,m1_31, Ha0,Ha1, a3);
        DOT8(m2_00,m2_01, Ha0,Ha1, q0); DOT8(m2_10,m2_11, Ha0,Ha1, q1);
        DOT8(m2_20,m2_21, Ha0,Ha1, q2); DOT8(m2_30,m2_31, Ha0,Ha1, q3);
        DOT8(m1_02,m1_03, Hb0,Hb1, a0); DOT8(m1_12,m1_13, Hb0,Hb1, a1);
        DOT8(m1_22,m1_23, Hb0,Hb1, a2); DOT8(m1_32,m1_33, Hb0,Hb1, a3);
        DOT8(m2_02,m2_03, Hb0,Hb1, q0); DOT8(m2_12,m2_13, Hb0,Hb1, q1);
        DOT8(m2_22,m2_23, Hb0,Hb1, q2); DOT8(m2_32,m2_33, Hb0,Hb1, q3);
        DOT8(m3_00,m3_01, Hc0,Hc1, q0); DOT8(m3_10,m3_11, Hc0,Hc1, q1);
        DOT8(m3_20,m3_21, Hc0,Hc1, q2); DOT8(m3_30,m3_31, Hc0,Hc1, q3);
        DOT8(m3_02,m3_03, Hd0,Hd1, q0); DOT8(m3_12,m3_13, Hd0,Hd1, q1);
        DOT8(m3_22,m3_23, Hd0,Hd1, q2); DOT8(m3_32,m3_33, Hd0,Hd1, q3);

        // ---- epilogue 1: h1(k)
        int ei = e;
        asm volatile("" : "+v"(ei));               // keep table reads in-loop
        float4 B1 = bct1[ei];
        float4 Wx = bctw[ei];
        a0 = red2(a0); a1 = red2(a1); a2 = red2(a2); a3 = red2(a3);
        float gi = actf(a0 + fmaf(x_cur, Wx.x, B1.x), 1.0f);
        float gf = actf(a1 + fmaf(x_cur, Wx.y, B1.y), 1.0f);
        float gg = actf(a2 + fmaf(x_cur, Wx.z, B1.z), 2.0f);
        float go = actf(a3 + fmaf(x_cur, Wx.w, B1.w), 1.0f);
        c1 = fmaf(gf, c1, gi * gg);
        float h1v = go * actf(c1, 2.0f);
        if (s == 0) ((uint16_t*)h1p[wbuf])[e] = f2h(h1v);

        // ---- epilogue 2: h2(k-1) + out(k-1) partial (skip at k=0)
        if (k > 0) {
            float4 B2 = bct2[ei];
            q0 = red2(q0); q1 = red2(q1); q2 = red2(q2); q3 = red2(q3);
            float hi = actf(q0 + B2.x, 1.0f);
            float hf = actf(q1 + B2.y, 1.0f);
            float hg = actf(q2 + B2.z, 2.0f);
            float ho = actf(q3 + B2.w, 1.0f);
            c2 = fmaf(hf, c2, hi * hg);
            float h2v = ho * actf(c2, 2.0f);
            if (s == 0) ((uint16_t*)h2p[wbuf])[e] = f2h(h2v);
            float part = wo * h2v;                 // wo==0 on s!=0 lanes
            part += __shfl_xor(part, 4,  64);
            part += __shfl_xor(part, 8,  64);
            part += __shfl_xor(part, 16, 64);
            part += __shfl_xor(part, 32, 64);
            if (l == 0) pbuf[rb][w] = part;
        }
        __syncthreads();   // single barrier: publish h1(k), h2(k-1), partials
        x_cur = x_nxt;
    }

    // ---- drain: out(T-1) partials were published at k=T (parity T&1)
    if (tid < 8) {
        float ssum = pbuf[T_STEPS & 1][tid];
        ssum += __shfl_xor(ssum, 1, 64);
        ssum += __shfl_xor(ssum, 2, 64);
        ssum += __shfl_xor(ssum, 4, 64);
        if (tid == 0) ob[T_STEPS - 1] = ssum + bo;
    }
}

extern "C" void kernel_launch(void* const* d_in, const int* in_sizes, int n_in,
                              void* d_out, int out_size, void* d_ws, size_t ws_size,
                              hipStream_t stream) {
    const float* x     = (const float*)d_in[0];
    const float* W_ih1 = (const float*)d_in[1];
    const float* W_hh1 = (const float*)d_in[2];
    const float* b_ih1 = (const float*)d_in[3];
    const float* b_hh1 = (const float*)d_in[4];
    const float* W_ih2 = (const float*)d_in[5];
    const float* W_hh2 = (const float*)d_in[6];
    const float* b_ih2 = (const float*)d_in[7];
    const float* b_hh2 = (const float*)d_in[8];
    const float* W_out = (const float*)d_in[9];
    const float* b_out = (const float*)d_in[10];
    float* out = (float*)d_out;

    const int B = in_sizes[0] / T_STEPS;   // 256
    hipLaunchKernelGGL(lstm_persistent, dim3(B), dim3(NT), 0, stream,
                       x, W_ih1, W_hh1, b_ih1, b_hh1,
                       W_ih2, W_hh2, b_ih2, b_hh2, W_out, b_out, out);
}